// Round 6
// baseline (239.953 us; speedup 1.0000x reference)
//
#include <hip/hip_runtime.h>
#include <hip/hip_bf16.h>

#define BS    8192
#define DIM   768
#define BM    256
#define BK    128   // one scaled-MFMA K per tile; 6 tiles total
#define NPERS 256   // persistent blocks; 128KB LDS caps residency at 1/CU, and
                    // round-4 (1024 blocks, 4 clean rounds) proved 256 co-reside.

typedef float f32x4 __attribute__((ext_vector_type(4)));
typedef int   i32x4 __attribute__((ext_vector_type(4)));
typedef int   i32x8 __attribute__((ext_vector_type(8)));

__device__ __forceinline__ void async16(const void* g, void* l) {
    __builtin_amdgcn_global_load_lds(
        (const __attribute__((address_space(1))) unsigned int*)g,
        (__attribute__((address_space(3))) unsigned int*)l,
        16, 0, 0);
}

// Round 10: single persistent fused kernel.
// GEMM schedule history: {2ph/8w, counted-vmcnt, 2ph/4w, 4ph-no-barriers,
// 4ph-barrier-paired} -> {118,118,107,102,128} us. At K=768 (6 K-iters) the
// deep-pipeline levers (T3/T4/T5) never reach steady state; round-4's
// 4-phase-no-barrier structure is the family optimum -> kept VERBATIM here.
// The attackable block is the ~67us constant non-gemm time (normalize BW
// floor is ~13us, finalize ~3us): inter-kernel drain+launch gaps. Fix:
// persistent blocks + software grid barrier (release fence -> device-scope
// atomic arrive -> spin -> acquire fence; round-5's ticket validated the
// cross-XCD atomic visibility pattern, absmax=0).
// Phase 1: block b normalizes rows [32b, 32b+32) of text+ctr (fp8 out, diag
//          sim); blocks 0..31 zero rowsum/colsum.
// Phase 2: grid barrier.
// Phase 3: 4 gemm tiles per block; rowBase is rep-invariant (A panel L2-hot),
//          tileCol = rep*8 + bid>>5 sweeps 4 column tiles.
// Phase 4: last-block ticket computes the final loss (round-5 pattern).
__global__ __launch_bounds__(512, 2) void fused_kernel(
    const float* __restrict__ text, const float* __restrict__ ctr,
    unsigned char* __restrict__ tq, unsigned char* __restrict__ cq,
    float* __restrict__ sim, float* __restrict__ rowsum, float* __restrict__ colsum,
    unsigned int* __restrict__ syncv, float* __restrict__ out) {
    __shared__ char ldsA[2][BM * BK];   // 2 x 32 KB
    __shared__ char ldsB[2][BM * BK];   // 2 x 32 KB

    const int tid  = threadIdx.x;
    const int bid  = blockIdx.x;
    const int wave = tid >> 6, lane = tid & 63;

    // ---------------- phase 1: normalize + zero sums ----------------
    if (bid < 32) {
        const int i = bid * 512 + tid;   // covers 16384 = 2*BS
        rowsum[i] = 0.f;
        colsum[i] = 0.f;
    }
#pragma unroll
    for (int r = 0; r < 4; ++r) {
        const int row = bid * 32 + wave * 4 + r;
        const size_t base = (size_t)row * DIM;
        float4 t[3], c[3];
        float st = 0.f, sc = 0.f, sd = 0.f;
#pragma unroll
        for (int i = 0; i < 3; ++i) {
            t[i] = *(const float4*)&text[base + lane * 4 + i * 256];
            c[i] = *(const float4*)&ctr [base + lane * 4 + i * 256];
            st += t[i].x*t[i].x + t[i].y*t[i].y + t[i].z*t[i].z + t[i].w*t[i].w;
            sc += c[i].x*c[i].x + c[i].y*c[i].y + c[i].z*c[i].z + c[i].w*c[i].w;
            sd += t[i].x*c[i].x + t[i].y*c[i].y + t[i].z*c[i].z + t[i].w*c[i].w;
        }
#pragma unroll
        for (int off = 1; off < 64; off <<= 1) {
            st += __shfl_xor(st, off);
            sc += __shfl_xor(sc, off);
            sd += __shfl_xor(sd, off);
        }
        const float invt = 1.0f / fmaxf(sqrtf(st), 1e-8f);
        const float invc = 1.0f / fmaxf(sqrtf(sc), 1e-8f);
#pragma unroll
        for (int i = 0; i < 3; ++i) {
            unsigned int wt = (unsigned int)__builtin_amdgcn_cvt_pk_fp8_f32(t[i].x * invt, t[i].y * invt, 0, false);
            wt = (unsigned int)__builtin_amdgcn_cvt_pk_fp8_f32(t[i].z * invt, t[i].w * invt, (int)wt, true);
            unsigned int wcq = (unsigned int)__builtin_amdgcn_cvt_pk_fp8_f32(c[i].x * invc, c[i].y * invc, 0, false);
            wcq = (unsigned int)__builtin_amdgcn_cvt_pk_fp8_f32(c[i].z * invc, c[i].w * invc, (int)wcq, true);
            *(unsigned int*)&tq[base + lane * 4 + i * 256] = wt;
            *(unsigned int*)&cq[base + lane * 4 + i * 256] = wcq;
        }
        if (lane == 0) sim[row] = sd * invt * invc;
    }

    // ---------------- phase 2: grid barrier ----------------
    __syncthreads();
    if (tid == 0) {
        __threadfence();   // release: tq/cq/sim/zeroed-sums visible device-wide
        __hip_atomic_fetch_add(&syncv[0], 1u, __ATOMIC_ACQ_REL, __HIP_MEMORY_SCOPE_AGENT);
        while (__hip_atomic_load(&syncv[0], __ATOMIC_RELAXED, __HIP_MEMORY_SCOPE_AGENT) < NPERS)
            __builtin_amdgcn_s_sleep(1);
        __threadfence();   // acquire: invalidate stale L1/L2 before reading tq/cq
    }
    __syncthreads();

    // ---------------- phase 3: gemm (round-4 schedule, verbatim) ----------------
    const int wr = wave >> 2, wc = wave & 3;   // 2x4 wave grid: 128x64 per wave
    const int quad = lane >> 4, l16 = lane & 15;

    // Tile map: rowBase rep-invariant; tileCol sweeps 4 columns.
    // bid = (b5<<5)|(b43<<3)|(b210): rowIdx = b210*4+b43 in [0,32),
    // tileCol = rep*8 + b5 -> all 32x32 tiles covered exactly once.
    const int rowBase = ((bid & 7) * 4 + ((bid >> 3) & 3)) * BM;
    const unsigned char* gA = tq + (size_t)rowBase * DIM;

    // Staging: 2048 16B chunks per operand tile; thread owns chunk tid+i*512
    // (quarter i). chunk p -> kc = p>>9, row = (p>>1)&255,
    // logical-half = (p&1) ^ (kc&1). LDS dest linear (wave-uniform + lane*16).
    int goff[4], p16[4];
#pragma unroll
    for (int i = 0; i < 4; ++i) {
        const int p  = tid + i * 512;
        const int kc = p >> 9;
        const int row = (p >> 1) & 255;
        const int hl  = (p & 1) ^ (kc & 1);
        goff[i] = row * DIM + kc * 32 + hl * 16;
        p16[i]  = p * 16;
    }

    // Fragment addressing: lane (quad,l16) needs k-block kc=quad of its row;
    // physical half = logical half ^ (quad&1).
    const int sw = quad & 1;
    int aoff[8], boff[4];
#pragma unroll
    for (int mt = 0; mt < 8; ++mt) aoff[mt] = quad * 8192 + (wr * 128 + mt * 16 + l16) * 32;
#pragma unroll
    for (int nt = 0; nt < 4; ++nt) boff[nt] = quad * 8192 + (wc * 64 + nt * 16 + l16) * 32;

#define STAGE(buf, t, i)                                            \
    do {                                                            \
        async16(gA + goff[i] + (t) * BK, &ldsA[buf][p16[i]]);       \
        async16(gB + goff[i] + (t) * BK, &ldsB[buf][p16[i]]);       \
    } while (0)
#define RD_A(dst, mt, buf)                                                     \
    do {                                                                       \
        i32x4 lo = *(const i32x4*)(ldsA[buf] + aoff[mt] + sw * 16);            \
        i32x4 hi = *(const i32x4*)(ldsA[buf] + aoff[mt] + (sw ^ 1) * 16);      \
        dst = __builtin_shufflevector(lo, hi, 0, 1, 2, 3, 4, 5, 6, 7);         \
    } while (0)
#define RD_B(dst, nt, buf)                                                     \
    do {                                                                       \
        i32x4 lo = *(const i32x4*)(ldsB[buf] + boff[nt] + sw * 16);            \
        i32x4 hi = *(const i32x4*)(ldsB[buf] + boff[nt] + (sw ^ 1) * 16);      \
        dst = __builtin_shufflevector(lo, hi, 0, 1, 2, 3, 4, 5, 6, 7);         \
    } while (0)
#define MFMA8(a0, a1, m0, m1)                                                  \
    do {                                                                       \
        acc[m0][0] = __builtin_amdgcn_mfma_scale_f32_16x16x128_f8f6f4(a0, bf0, acc[m0][0], 0, 0, 0, 127, 0, 127); \
        acc[m0][1] = __builtin_amdgcn_mfma_scale_f32_16x16x128_f8f6f4(a0, bf1, acc[m0][1], 0, 0, 0, 127, 0, 127); \
        acc[m0][2] = __builtin_amdgcn_mfma_scale_f32_16x16x128_f8f6f4(a0, bf2, acc[m0][2], 0, 0, 0, 127, 0, 127); \
        acc[m0][3] = __builtin_amdgcn_mfma_scale_f32_16x16x128_f8f6f4(a0, bf3, acc[m0][3], 0, 0, 0, 127, 0, 127); \
        acc[m1][0] = __builtin_amdgcn_mfma_scale_f32_16x16x128_f8f6f4(a1, bf0, acc[m1][0], 0, 0, 0, 127, 0, 127); \
        acc[m1][1] = __builtin_amdgcn_mfma_scale_f32_16x16x128_f8f6f4(a1, bf1, acc[m1][1], 0, 0, 0, 127, 0, 127); \
        acc[m1][2] = __builtin_amdgcn_mfma_scale_f32_16x16x128_f8f6f4(a1, bf2, acc[m1][2], 0, 0, 0, 127, 0, 127); \
        acc[m1][3] = __builtin_amdgcn_mfma_scale_f32_16x16x128_f8f6f4(a1, bf3, acc[m1][3], 0, 0, 0, 127, 0, 127); \
    } while (0)
#define SBAR()  __builtin_amdgcn_sched_barrier(0)

#pragma unroll 1
    for (int rep = 0; rep < 4; ++rep) {
        const int colBase = (rep * 8 + (bid >> 5)) * BM;
        const unsigned char* gB = cq + (size_t)colBase * DIM;

        f32x4 acc[8][4];
#pragma unroll
        for (int mt = 0; mt < 8; ++mt)
#pragma unroll
            for (int nt = 0; nt < 4; ++nt)
                acc[mt][nt] = (f32x4){0.f, 0.f, 0.f, 0.f};

        // All waves past the previous rep's LDS reads before restaging.
        __syncthreads();

        // Prologue: stage tile 0 fully + tile 1 quarter 0; wait vmcnt(2).
        STAGE(0, 0, 0); STAGE(0, 0, 1); STAGE(0, 0, 2); STAGE(0, 0, 3);
        SBAR();
        STAGE(1, 1, 0);
        SBAR();
        asm volatile("s_waitcnt vmcnt(2)" ::: "memory");
        SBAR();
        __builtin_amdgcn_s_barrier();

#pragma unroll
        for (int t = 0; t < 6; ++t) {
            const int cur = t & 1;
            i32x8 bf0, bf1, bf2, bf3, aE0, aE1, aO0, aO1;

            // Pre-phase reads: all B (8 b128) + A pair0 (4 b128).
            RD_B(bf0, 0, cur); RD_B(bf1, 1, cur); RD_B(bf2, 2, cur); RD_B(bf3, 3, cur);
            RD_A(aE0, 0, cur); RD_A(aE1, 1, cur);

            // ph0: prefetch A pair1; stage Q1(t+1); wait(4); MFMA pair0.
            RD_A(aO0, 2, cur); RD_A(aO1, 3, cur);
            if (t < 5) STAGE(cur ^ 1, t + 1, 1);
            asm volatile("s_waitcnt lgkmcnt(4)" ::: "memory");
            SBAR();
            __builtin_amdgcn_s_setprio(1);
            MFMA8(aE0, aE1, 0, 1);
            __builtin_amdgcn_s_setprio(0);

            // ph1: prefetch A pair2; stage Q2(t+1); wait(4); MFMA pair1.
            RD_A(aE0, 4, cur); RD_A(aE1, 5, cur);
            if (t < 5) STAGE(cur ^ 1, t + 1, 2);
            asm volatile("s_waitcnt lgkmcnt(4)" ::: "memory");
            SBAR();
            __builtin_amdgcn_s_setprio(1);
            MFMA8(aO0, aO1, 2, 3);
            __builtin_amdgcn_s_setprio(0);

            // ph2: prefetch A pair3; stage Q3(t+1); wait(4); MFMA pair2.
            RD_A(aO0, 6, cur); RD_A(aO1, 7, cur);
            if (t < 5) STAGE(cur ^ 1, t + 1, 3);
            asm volatile("s_waitcnt lgkmcnt(4)" ::: "memory");
            SBAR();
            __builtin_amdgcn_s_setprio(1);
            MFMA8(aE0, aE1, 4, 5);
            __builtin_amdgcn_s_setprio(0);

            // ph3: wait(0); MFMA pair3.
            asm volatile("s_waitcnt lgkmcnt(0)" ::: "memory");
            SBAR();
            __builtin_amdgcn_s_setprio(1);
            MFMA8(aO0, aO1, 6, 7);
            __builtin_amdgcn_s_setprio(0);

            // Boundary: mid-barrier (reads of buf[cur] done block-wide) ->
            // issue t+2.Q0 into buf[cur]; counted vmcnt; barrier.
            if (t < 5) {
                __builtin_amdgcn_s_barrier();
                SBAR();
                if (t < 4) {
                    STAGE(cur, t + 2, 0);
                    SBAR();
                    asm volatile("s_waitcnt vmcnt(2)" ::: "memory");
                } else {
                    asm volatile("s_waitcnt vmcnt(0)" ::: "memory");
                }
                SBAR();
                __builtin_amdgcn_s_barrier();
            }
        }

        // Epilogue. D layout: col = l16 (ctr idx), row = quad*4 + reg (text idx).
        float rp[8][4];
        float cp[4];
#pragma unroll
        for (int mt = 0; mt < 8; ++mt)
#pragma unroll
            for (int r = 0; r < 4; ++r) rp[mt][r] = 0.f;
#pragma unroll
        for (int nt = 0; nt < 4; ++nt) cp[nt] = 0.f;

#pragma unroll
        for (int mt = 0; mt < 8; ++mt)
#pragma unroll
            for (int nt = 0; nt < 4; ++nt)
#pragma unroll
                for (int r = 0; r < 4; ++r) {
                    const float e = __expf(acc[mt][nt][r]);   // S in [-1,1]
                    rp[mt][r] += e;
                    cp[nt]    += e;
                }

#pragma unroll
        for (int mt = 0; mt < 8; ++mt)
#pragma unroll
            for (int r = 0; r < 4; ++r) {
                float v = rp[mt][r];
                v += __shfl_xor(v, 1);
                v += __shfl_xor(v, 2);
                v += __shfl_xor(v, 4);
                v += __shfl_xor(v, 8);
                rp[mt][r] = v;
            }
        if (l16 == 0) {
#pragma unroll
            for (int mt = 0; mt < 8; ++mt)
#pragma unroll
                for (int r = 0; r < 4; ++r)
                    atomicAdd(&rowsum[rowBase + wr * 128 + mt * 16 + quad * 4 + r], rp[mt][r]);
        }
#pragma unroll
        for (int nt = 0; nt < 4; ++nt) {
            float v = cp[nt];
            v += __shfl_xor(v, 16);
            v += __shfl_xor(v, 32);
            if (quad == 0)
                atomicAdd(&colsum[colBase + wc * 64 + nt * 16 + l16], v);
        }
    }

    // ---------------- phase 4: last-block finalize ----------------
    unsigned int* tick = (unsigned int*)&ldsA[0][0];
    __syncthreads();               // drains this block's atomics (vmcnt 0)
    if (tid == 0) {
        __threadfence();           // order atomics before ticket
        tick[0] = __hip_atomic_fetch_add(&syncv[1], 1u, __ATOMIC_ACQ_REL, __HIP_MEMORY_SCOPE_AGENT);
    }
    __syncthreads();
    if (tick[0] == NPERS - 1) {
        float a2 = 0.f;
#pragma unroll
        for (int k = 0; k < 16; ++k) {
            const int i = tid + k * 512;
            const float rs = __hip_atomic_load(&rowsum[i], __ATOMIC_RELAXED, __HIP_MEMORY_SCOPE_AGENT);
            const float cs = __hip_atomic_load(&colsum[i], __ATOMIC_RELAXED, __HIP_MEMORY_SCOPE_AGENT);
            a2 += __logf(rs) + __logf(cs) - 2.f * sim[i];
        }
#pragma unroll
        for (int off = 1; off < 64; off <<= 1) a2 += __shfl_xor(a2, off);
        float* red = (float*)&ldsB[0][0];
        if (lane == 0) red[wave] = a2;
        __syncthreads();
        if (tid == 0) {
            float s = 0.f;
#pragma unroll
            for (int w = 0; w < 8; ++w) s += red[w];
            out[0] = s / (float)BS;
        }
    }
}

extern "C" void kernel_launch(void* const* d_in, const int* in_sizes, int n_in,
                              void* d_out, int out_size, void* d_ws, size_t ws_size,
                              hipStream_t stream) {
    const float* text = (const float*)d_in[0];
    const float* ctr  = (const float*)d_in[1];

    char* ws = (char*)d_ws;
    const size_t embBytes = (size_t)BS * DIM;   // fp8: 6,291,456 bytes each
    unsigned char* tq = (unsigned char*)ws;
    unsigned char* cq = (unsigned char*)(ws + embBytes);
    float* sim    = (float*)(ws + 2 * embBytes);
    float* rowsum = (float*)(ws + 2 * embBytes + BS * sizeof(float));
    float* colsum = (float*)(ws + 2 * embBytes + 2 * BS * sizeof(float));
    unsigned int* syncv = (unsigned int*)(ws + 2 * embBytes + 3 * BS * sizeof(float));

    hipMemsetAsync(syncv, 0, 8, stream);   // arm barrier + ticket counters

    fused_kernel<<<NPERS, 512, 0, stream>>>(text, ctr, tq, cq, sim,
                                            rowsum, colsum, syncv, (float*)d_out);
}

// Round 7
// 193.906 us; speedup vs baseline: 1.2375x; 1.2375x over previous
//
#include <hip/hip_runtime.h>
#include <hip/hip_bf16.h>

#define BS   8192
#define DIM  768
#define BM   256
#define BK   128   // one scaled-MFMA K per tile; 6 tiles total
#define NBLK ((BS / BM) * (BS / BM))   // 1024 gemm blocks

typedef float f32x4 __attribute__((ext_vector_type(4)));
typedef int   i32x4 __attribute__((ext_vector_type(4)));
typedef int   i32x8 __attribute__((ext_vector_type(8)));

__device__ __forceinline__ void async16(const void* g, void* l) {
    __builtin_amdgcn_global_load_lds(
        (const __attribute__((address_space(1))) unsigned int*)g,
        (__attribute__((address_space(3))) unsigned int*)l,
        16, 0, 0);
}

// One wave per row: L2-norm both embeddings, emit fp8 e4m3, diag sim in fp32.
// Blocks 0..63 also zero rowsum/colsum; block 0 zeroes the done-counter.
__global__ __launch_bounds__(256) void normalize_kernel(
    const float* __restrict__ text, const float* __restrict__ ctr,
    unsigned char* __restrict__ tq, unsigned char* __restrict__ cq,
    float* __restrict__ sim, float* __restrict__ rowsum, float* __restrict__ colsum,
    unsigned int* __restrict__ cnt) {
    if (blockIdx.x < 64) {
        const int i = blockIdx.x * 256 + threadIdx.x;   // covers 16384 = 2*BS
        rowsum[i] = 0.f;
        colsum[i] = 0.f;
    }
    if (blockIdx.x == 0 && threadIdx.x == 0) cnt[0] = 0u;
    const int lane = threadIdx.x & 63;
    const int row  = blockIdx.x * 4 + (threadIdx.x >> 6);
    const size_t base = (size_t)row * DIM;

    float4 t[3], c[3];
    float st = 0.f, sc = 0.f, sd = 0.f;
#pragma unroll
    for (int i = 0; i < 3; ++i) {
        t[i] = *(const float4*)&text[base + lane * 4 + i * 256];
        c[i] = *(const float4*)&ctr [base + lane * 4 + i * 256];
        st += t[i].x*t[i].x + t[i].y*t[i].y + t[i].z*t[i].z + t[i].w*t[i].w;
        sc += c[i].x*c[i].x + c[i].y*c[i].y + c[i].z*c[i].z + c[i].w*c[i].w;
        sd += t[i].x*c[i].x + t[i].y*c[i].y + t[i].z*c[i].z + t[i].w*c[i].w;
    }
#pragma unroll
    for (int off = 1; off < 64; off <<= 1) {
        st += __shfl_xor(st, off);
        sc += __shfl_xor(sc, off);
        sd += __shfl_xor(sd, off);
    }
    const float invt = 1.0f / fmaxf(sqrtf(st), 1e-8f);
    const float invc = 1.0f / fmaxf(sqrtf(sc), 1e-8f);
#pragma unroll
    for (int i = 0; i < 3; ++i) {
        unsigned int wt = (unsigned int)__builtin_amdgcn_cvt_pk_fp8_f32(t[i].x * invt, t[i].y * invt, 0, false);
        wt = (unsigned int)__builtin_amdgcn_cvt_pk_fp8_f32(t[i].z * invt, t[i].w * invt, (int)wt, true);
        unsigned int wcq = (unsigned int)__builtin_amdgcn_cvt_pk_fp8_f32(c[i].x * invc, c[i].y * invc, 0, false);
        wcq = (unsigned int)__builtin_amdgcn_cvt_pk_fp8_f32(c[i].z * invc, c[i].w * invc, (int)wcq, true);
        *(unsigned int*)&tq[base + lane * 4 + i * 256] = wt;
        *(unsigned int*)&cq[base + lane * 4 + i * 256] = wcq;
    }
    if (lane == 0) sim[row] = sd * invt * invc;
}

// MX-scaled fp8 GEMM (unit scales) -- round 11: REVERT to the round-4/9
// structure, the session optimum (gemm 102us, total 169.4us).
// Landscape sampled: {2ph/8w=118, counted-vmcnt=118, 2ph/4w/3blk=107,
// 4ph-no-barriers=102, 4ph-barrier-paired=128, persistent+grid-barrier=240}.
// All pipes <25% busy in every variant; at K=768 (6 K-iters) the deep-pipeline
// catalog gains don't reach steady state (guide m248v2: 8ph/2ph = 1.10x at
// K=1024 -- matches our 107->102). This 4-phase counted-vmcnt schedule is the
// plain-HIP optimum for this shape; further requires hand-asm interleave.
// Phase p: {ds_read A-pair(p+1) || stage quarter(t+1)}; lgkmcnt(4);
//          setprio(1) 8xMFMA setprio(0).  NO per-phase barriers (round 5
//          proved they regress at this K). Boundary: lgkm(0); mid-barrier;
//          stage t+2.Q0 into buf[cur]; MFMA pair3; vmcnt(2) (t+2.Q0 stays in
//          flight -- never drain to 0 mid-loop); barrier.
// LDS layout per buffer: [kc(4)][row(256)][32B], halves swizzled by (kc&1):
// conflict-free (SQ_LDS_BANK_CONFLICT = 0 in all rounds).
// Fused finalize: last-block ticket (validated round 4, absmax 0).
__global__ __launch_bounds__(512, 2) void gemm_lse_kernel(
    const unsigned char* __restrict__ tq, const unsigned char* __restrict__ cq,
    float* __restrict__ rowsum, float* __restrict__ colsum,
    const float* __restrict__ sim, unsigned int* __restrict__ cnt,
    float* __restrict__ out) {
    __shared__ char ldsA[2][BM * BK];   // 2 x 32 KB
    __shared__ char ldsB[2][BM * BK];   // 2 x 32 KB

    const int tid = threadIdx.x;

    // XCD-banded swizzle: XCD x owns tile-rows [4x, 4x+4), sweeping columns.
    const int bid = blockIdx.x;              // 1024 blocks = 32x32 tiles
    const int xcd = bid & 7, idx = bid >> 3;
    const int tileCol = idx >> 2, rowInBand = idx & 3;
    const int rowBase = (xcd * 4 + rowInBand) * BM;
    const int colBase = tileCol * BM;

    const int wave = tid >> 6, lane = tid & 63;
    const int wr = wave >> 2, wc = wave & 3;   // 2x4 wave grid: 128x64 per wave
    const int quad = lane >> 4, l16 = lane & 15;

    // Staging: 2048 16B chunks per operand tile; thread owns chunk tid+i*512
    // (quarter i). chunk p -> kc = p>>9, row = (p>>1)&255,
    // logical-half = (p&1) ^ (kc&1). LDS dest linear (wave-uniform + lane*16).
    int goff[4], p16[4];
#pragma unroll
    for (int i = 0; i < 4; ++i) {
        const int p  = tid + i * 512;
        const int kc = p >> 9;
        const int row = (p >> 1) & 255;
        const int hl  = (p & 1) ^ (kc & 1);
        goff[i] = row * DIM + kc * 32 + hl * 16;
        p16[i]  = p * 16;
    }
    const unsigned char* gA = tq + (size_t)rowBase * DIM;
    const unsigned char* gB = cq + (size_t)colBase * DIM;

#define STAGE(buf, t, i)                                            \
    do {                                                            \
        async16(gA + goff[i] + (t) * BK, &ldsA[buf][p16[i]]);       \
        async16(gB + goff[i] + (t) * BK, &ldsB[buf][p16[i]]);       \
    } while (0)

    // Fragment addressing: lane (quad,l16) needs k-block kc=quad of its row;
    // physical half = logical half ^ (quad&1).
    const int sw = quad & 1;
    int aoff[8], boff[4];
#pragma unroll
    for (int mt = 0; mt < 8; ++mt) aoff[mt] = quad * 8192 + (wr * 128 + mt * 16 + l16) * 32;
#pragma unroll
    for (int nt = 0; nt < 4; ++nt) boff[nt] = quad * 8192 + (wc * 64 + nt * 16 + l16) * 32;

#define RD_A(dst, mt, buf)                                                     \
    do {                                                                       \
        i32x4 lo = *(const i32x4*)(ldsA[buf] + aoff[mt] + sw * 16);            \
        i32x4 hi = *(const i32x4*)(ldsA[buf] + aoff[mt] + (sw ^ 1) * 16);      \
        dst = __builtin_shufflevector(lo, hi, 0, 1, 2, 3, 4, 5, 6, 7);         \
    } while (0)
#define RD_B(dst, nt, buf)                                                     \
    do {                                                                       \
        i32x4 lo = *(const i32x4*)(ldsB[buf] + boff[nt] + sw * 16);            \
        i32x4 hi = *(const i32x4*)(ldsB[buf] + boff[nt] + (sw ^ 1) * 16);      \
        dst = __builtin_shufflevector(lo, hi, 0, 1, 2, 3, 4, 5, 6, 7);         \
    } while (0)
#define MFMA8(a0, a1, m0, m1)                                                  \
    do {                                                                       \
        acc[m0][0] = __builtin_amdgcn_mfma_scale_f32_16x16x128_f8f6f4(a0, bf0, acc[m0][0], 0, 0, 0, 127, 0, 127); \
        acc[m0][1] = __builtin_amdgcn_mfma_scale_f32_16x16x128_f8f6f4(a0, bf1, acc[m0][1], 0, 0, 0, 127, 0, 127); \
        acc[m0][2] = __builtin_amdgcn_mfma_scale_f32_16x16x128_f8f6f4(a0, bf2, acc[m0][2], 0, 0, 0, 127, 0, 127); \
        acc[m0][3] = __builtin_amdgcn_mfma_scale_f32_16x16x128_f8f6f4(a0, bf3, acc[m0][3], 0, 0, 0, 127, 0, 127); \
        acc[m1][0] = __builtin_amdgcn_mfma_scale_f32_16x16x128_f8f6f4(a1, bf0, acc[m1][0], 0, 0, 0, 127, 0, 127); \
        acc[m1][1] = __builtin_amdgcn_mfma_scale_f32_16x16x128_f8f6f4(a1, bf1, acc[m1][1], 0, 0, 0, 127, 0, 127); \
        acc[m1][2] = __builtin_amdgcn_mfma_scale_f32_16x16x128_f8f6f4(a1, bf2, acc[m1][2], 0, 0, 0, 127, 0, 127); \
        acc[m1][3] = __builtin_amdgcn_mfma_scale_f32_16x16x128_f8f6f4(a1, bf3, acc[m1][3], 0, 0, 0, 127, 0, 127); \
    } while (0)
#define SBAR()  __builtin_amdgcn_sched_barrier(0)

    f32x4 acc[8][4];
#pragma unroll
    for (int mt = 0; mt < 8; ++mt)
#pragma unroll
        for (int nt = 0; nt < 4; ++nt)
            acc[mt][nt] = (f32x4){0.f, 0.f, 0.f, 0.f};

    // Prologue: stage tile 0 fully (8 loads) + tile 1 quarter 0 (2 loads);
    // wait vmcnt(2): tile 0 landed, t1.Q0 in flight.
    STAGE(0, 0, 0); STAGE(0, 0, 1); STAGE(0, 0, 2); STAGE(0, 0, 3);
    SBAR();
    STAGE(1, 1, 0);
    SBAR();
    asm volatile("s_waitcnt vmcnt(2)" ::: "memory");
    SBAR();
    __builtin_amdgcn_s_barrier();

#pragma unroll
    for (int t = 0; t < 6; ++t) {
        const int cur = t & 1;
        i32x8 bf0, bf1, bf2, bf3, aE0, aE1, aO0, aO1;

        // Pre-phase reads: all B (8 b128) + A pair0 (4 b128).
        RD_B(bf0, 0, cur); RD_B(bf1, 1, cur); RD_B(bf2, 2, cur); RD_B(bf3, 3, cur);
        RD_A(aE0, 0, cur); RD_A(aE1, 1, cur);

        // ph0: prefetch A pair1; stage Q1(t+1); wait(4); MFMA pair0.
        RD_A(aO0, 2, cur); RD_A(aO1, 3, cur);
        if (t < 5) STAGE(cur ^ 1, t + 1, 1);
        asm volatile("s_waitcnt lgkmcnt(4)" ::: "memory");
        SBAR();
        __builtin_amdgcn_s_setprio(1);
        MFMA8(aE0, aE1, 0, 1);
        __builtin_amdgcn_s_setprio(0);

        // ph1: prefetch A pair2; stage Q2(t+1); wait(4); MFMA pair1.
        RD_A(aE0, 4, cur); RD_A(aE1, 5, cur);
        if (t < 5) STAGE(cur ^ 1, t + 1, 2);
        asm volatile("s_waitcnt lgkmcnt(4)" ::: "memory");
        SBAR();
        __builtin_amdgcn_s_setprio(1);
        MFMA8(aO0, aO1, 2, 3);
        __builtin_amdgcn_s_setprio(0);

        // ph2: prefetch A pair3; stage Q3(t+1); wait(4); MFMA pair2.
        RD_A(aO0, 6, cur); RD_A(aO1, 7, cur);
        if (t < 5) STAGE(cur ^ 1, t + 1, 3);
        asm volatile("s_waitcnt lgkmcnt(4)" ::: "memory");
        SBAR();
        __builtin_amdgcn_s_setprio(1);
        MFMA8(aE0, aE1, 4, 5);
        __builtin_amdgcn_s_setprio(0);

        // ph3: wait(0); MFMA pair3.
        asm volatile("s_waitcnt lgkmcnt(0)" ::: "memory");
        SBAR();
        __builtin_amdgcn_s_setprio(1);
        MFMA8(aO0, aO1, 6, 7);
        __builtin_amdgcn_s_setprio(0);

        // Boundary: mid-barrier (reads of buf[cur] done block-wide) ->
        // issue t+2.Q0 into buf[cur]; counted vmcnt; barrier.
        if (t < 5) {
            __builtin_amdgcn_s_barrier();
            SBAR();
            if (t < 4) {
                STAGE(cur, t + 2, 0);
                SBAR();
                asm volatile("s_waitcnt vmcnt(2)" ::: "memory");
            } else {
                asm volatile("s_waitcnt vmcnt(0)" ::: "memory");
            }
            SBAR();
            __builtin_amdgcn_s_barrier();
        }
    }

    // Epilogue. D layout: col = l16 (ctr idx), row = quad*4 + reg (text idx).
    float rp[8][4];   // [mt][reg] partials over this wave's 64 cols
    float cp[4];      // [nt] partials over this wave's 128 rows
#pragma unroll
    for (int mt = 0; mt < 8; ++mt)
#pragma unroll
        for (int r = 0; r < 4; ++r) rp[mt][r] = 0.f;
#pragma unroll
    for (int nt = 0; nt < 4; ++nt) cp[nt] = 0.f;

#pragma unroll
    for (int mt = 0; mt < 8; ++mt)
#pragma unroll
        for (int nt = 0; nt < 4; ++nt)
#pragma unroll
            for (int r = 0; r < 4; ++r) {
                const float e = __expf(acc[mt][nt][r]);   // S in [-1,1]: no max needed
                rp[mt][r] += e;
                cp[nt]    += e;
            }

#pragma unroll
    for (int mt = 0; mt < 8; ++mt)
#pragma unroll
        for (int r = 0; r < 4; ++r) {
            float v = rp[mt][r];
            v += __shfl_xor(v, 1);
            v += __shfl_xor(v, 2);
            v += __shfl_xor(v, 4);
            v += __shfl_xor(v, 8);
            rp[mt][r] = v;
        }
    if (l16 == 0) {
#pragma unroll
        for (int mt = 0; mt < 8; ++mt)
#pragma unroll
            for (int r = 0; r < 4; ++r)
                atomicAdd(&rowsum[rowBase + wr * 128 + mt * 16 + quad * 4 + r], rp[mt][r]);
    }
#pragma unroll
    for (int nt = 0; nt < 4; ++nt) {
        float v = cp[nt];
        v += __shfl_xor(v, 16);
        v += __shfl_xor(v, 32);
        if (quad == 0)
            atomicAdd(&colsum[colBase + wc * 64 + nt * 16 + l16], v);
    }

    // ---- fused finalize: last-finished block reduces the loss ----
    unsigned int* tick = (unsigned int*)&ldsA[0][0];   // LDS reuse (reads all drained)
    __syncthreads();               // block's atomics complete (implicit vmcnt(0))
    if (tid == 0) {
        __threadfence();           // order atomics before ticket (agent scope)
        tick[0] = __hip_atomic_fetch_add(cnt, 1u, __ATOMIC_ACQ_REL, __HIP_MEMORY_SCOPE_AGENT);
    }
    __syncthreads();
    if (tick[0] == NBLK - 1) {
        float a2 = 0.f;
#pragma unroll
        for (int k = 0; k < 16; ++k) {
            const int i = tid + k * 512;
            const float rs = __hip_atomic_load(&rowsum[i], __ATOMIC_RELAXED, __HIP_MEMORY_SCOPE_AGENT);
            const float cs = __hip_atomic_load(&colsum[i], __ATOMIC_RELAXED, __HIP_MEMORY_SCOPE_AGENT);
            a2 += __logf(rs) + __logf(cs) - 2.f * sim[i];
        }
#pragma unroll
        for (int off = 1; off < 64; off <<= 1) a2 += __shfl_xor(a2, off);
        float* red = (float*)&ldsB[0][0];
        if (lane == 0) red[wave] = a2;
        __syncthreads();
        if (tid == 0) {
            float s = 0.f;
#pragma unroll
            for (int w = 0; w < 8; ++w) s += red[w];
            out[0] = s / (float)BS;
        }
    }
}

extern "C" void kernel_launch(void* const* d_in, const int* in_sizes, int n_in,
                              void* d_out, int out_size, void* d_ws, size_t ws_size,
                              hipStream_t stream) {
    const float* text = (const float*)d_in[0];
    const float* ctr  = (const float*)d_in[1];

    char* ws = (char*)d_ws;
    const size_t embBytes = (size_t)BS * DIM;   // fp8: 6,291,456 bytes each
    unsigned char* tq = (unsigned char*)ws;
    unsigned char* cq = (unsigned char*)(ws + embBytes);
    float* sim    = (float*)(ws + 2 * embBytes);
    float* rowsum = (float*)(ws + 2 * embBytes + BS * sizeof(float));
    float* colsum = (float*)(ws + 2 * embBytes + 2 * BS * sizeof(float));
    unsigned int* cnt = (unsigned int*)(ws + 2 * embBytes + 3 * BS * sizeof(float));

    normalize_kernel<<<BS / 4, 256, 0, stream>>>(text, ctr, tq, cq, sim, rowsum, colsum, cnt);

    gemm_lse_kernel<<<NBLK, 512, 0, stream>>>(tq, cq, rowsum, colsum, sim, cnt, (float*)d_out);
}

// Round 8
// 170.388 us; speedup vs baseline: 1.4083x; 1.1380x over previous
//
#include <hip/hip_runtime.h>
#include <hip/hip_bf16.h>

#define BS   8192
#define DIM  768
#define BM   256
#define BK   128   // one scaled-MFMA K per tile; 6 tiles total

typedef float f32x4 __attribute__((ext_vector_type(4)));
typedef int   i32x4 __attribute__((ext_vector_type(4)));
typedef int   i32x8 __attribute__((ext_vector_type(8)));

__device__ __forceinline__ void async16(const void* g, void* l) {
    __builtin_amdgcn_global_load_lds(
        (const __attribute__((address_space(1))) unsigned int*)g,
        (__attribute__((address_space(3))) unsigned int*)l,
        16, 0, 0);
}

// One wave per row: L2-norm both embeddings, emit fp8 e4m3, diag sim in fp32.
// Blocks 0..63 also zero rowsum/colsum (replaces the hipMemsetAsync dispatch).
__global__ __launch_bounds__(256) void normalize_kernel(
    const float* __restrict__ text, const float* __restrict__ ctr,
    unsigned char* __restrict__ tq, unsigned char* __restrict__ cq,
    float* __restrict__ sim, float* __restrict__ rowsum, float* __restrict__ colsum) {
    if (blockIdx.x < 64) {
        const int i = blockIdx.x * 256 + threadIdx.x;   // covers 16384 = 2*BS
        rowsum[i] = 0.f;
        colsum[i] = 0.f;
    }
    const int lane = threadIdx.x & 63;
    const int row  = blockIdx.x * 4 + (threadIdx.x >> 6);
    const size_t base = (size_t)row * DIM;

    float4 t[3], c[3];
    float st = 0.f, sc = 0.f, sd = 0.f;
#pragma unroll
    for (int i = 0; i < 3; ++i) {
        t[i] = *(const float4*)&text[base + lane * 4 + i * 256];
        c[i] = *(const float4*)&ctr [base + lane * 4 + i * 256];
        st += t[i].x*t[i].x + t[i].y*t[i].y + t[i].z*t[i].z + t[i].w*t[i].w;
        sc += c[i].x*c[i].x + c[i].y*c[i].y + c[i].z*c[i].z + c[i].w*c[i].w;
        sd += t[i].x*c[i].x + t[i].y*c[i].y + t[i].z*c[i].z + t[i].w*c[i].w;
    }
#pragma unroll
    for (int off = 1; off < 64; off <<= 1) {
        st += __shfl_xor(st, off);
        sc += __shfl_xor(sc, off);
        sd += __shfl_xor(sd, off);
    }
    const float invt = 1.0f / fmaxf(sqrtf(st), 1e-8f);
    const float invc = 1.0f / fmaxf(sqrtf(sc), 1e-8f);
#pragma unroll
    for (int i = 0; i < 3; ++i) {
        unsigned int wt = (unsigned int)__builtin_amdgcn_cvt_pk_fp8_f32(t[i].x * invt, t[i].y * invt, 0, false);
        wt = (unsigned int)__builtin_amdgcn_cvt_pk_fp8_f32(t[i].z * invt, t[i].w * invt, (int)wt, true);
        unsigned int wcq = (unsigned int)__builtin_amdgcn_cvt_pk_fp8_f32(c[i].x * invc, c[i].y * invc, 0, false);
        wcq = (unsigned int)__builtin_amdgcn_cvt_pk_fp8_f32(c[i].z * invc, c[i].w * invc, (int)wcq, true);
        *(unsigned int*)&tq[base + lane * 4 + i * 256] = wt;
        *(unsigned int*)&cq[base + lane * 4 + i * 256] = wcq;
    }
    if (lane == 0) sim[row] = sd * invt * invc;
}

// MX-scaled fp8 GEMM (unit scales) -- round 12: EXACT round-4 configuration,
// the session optimum (gemm 102us, total 169.4us). Cross-round A/B isolated
// the fused-finalize tail as a 21us REGRESSION (R4 no-tail=102 vs R7
// with-tail=123 vs R5 +barriers=128): 1024x device-scope threadfence (L2
// writeback on gfx950) + hot agent-scope ticket line across 8 non-coherent
// XCDs pollutes concurrent blocks. Separate 3us finalize dispatch is cheaper.
// Schedule landscape sampled across the session: {2ph/8w=118, counted-
// vmcnt=118, 2ph/4w/3blk=107, 4ph-no-barriers=102, 4ph+phase-barriers=128,
// persistent+grid-barrier=240}. At K=768 (6 K-iters) deep-pipeline catalog
// gains never reach steady state (guide m248v2: 8ph/2ph=1.10x at K=1024);
// this 4-phase counted-vmcnt structure is the plain-HIP optimum here.
// Phase p: {ds_read A-pair(p+1) || stage quarter(t+1)}; lgkmcnt(4);
//          setprio(1) 8xMFMA setprio(0).  NO per-phase barriers.
// Boundary: lgkm(0); mid-barrier; stage t+2.Q0 into buf[cur]; MFMA pair3;
//          vmcnt(2) (t+2.Q0 stays in flight -- never 0 mid-loop); barrier.
// LDS layout per buffer: [kc(4)][row(256)][32B], halves swizzled by (kc&1):
// conflict-free (SQ_LDS_BANK_CONFLICT = 0 in all rounds).
__global__ __launch_bounds__(512, 2) void gemm_lse_kernel(
    const unsigned char* __restrict__ tq, const unsigned char* __restrict__ cq,
    float* __restrict__ rowsum, float* __restrict__ colsum) {
    __shared__ char ldsA[2][BM * BK];   // 2 x 32 KB
    __shared__ char ldsB[2][BM * BK];   // 2 x 32 KB

    const int tid = threadIdx.x;

    // XCD-banded swizzle: XCD x owns tile-rows [4x, 4x+4), sweeping columns.
    const int bid = blockIdx.x;              // 1024 blocks = 32x32 tiles
    const int xcd = bid & 7, idx = bid >> 3;
    const int tileCol = idx >> 2, rowInBand = idx & 3;
    const int rowBase = (xcd * 4 + rowInBand) * BM;
    const int colBase = tileCol * BM;

    const int wave = tid >> 6, lane = tid & 63;
    const int wr = wave >> 2, wc = wave & 3;   // 2x4 wave grid: 128x64 per wave
    const int quad = lane >> 4, l16 = lane & 15;

    // Staging: 2048 16B chunks per operand tile; thread owns chunk tid+i*512
    // (quarter i). chunk p -> kc = p>>9, row = (p>>1)&255,
    // logical-half = (p&1) ^ (kc&1). LDS dest linear (wave-uniform + lane*16).
    int goff[4], p16[4];
#pragma unroll
    for (int i = 0; i < 4; ++i) {
        const int p  = tid + i * 512;
        const int kc = p >> 9;
        const int row = (p >> 1) & 255;
        const int hl  = (p & 1) ^ (kc & 1);
        goff[i] = row * DIM + kc * 32 + hl * 16;
        p16[i]  = p * 16;
    }
    const unsigned char* gA = tq + (size_t)rowBase * DIM;
    const unsigned char* gB = cq + (size_t)colBase * DIM;

#define STAGE(buf, t, i)                                            \
    do {                                                            \
        async16(gA + goff[i] + (t) * BK, &ldsA[buf][p16[i]]);       \
        async16(gB + goff[i] + (t) * BK, &ldsB[buf][p16[i]]);       \
    } while (0)

    // Fragment addressing: lane (quad,l16) needs k-block kc=quad of its row;
    // physical half = logical half ^ (quad&1).
    const int sw = quad & 1;
    int aoff[8], boff[4];
#pragma unroll
    for (int mt = 0; mt < 8; ++mt) aoff[mt] = quad * 8192 + (wr * 128 + mt * 16 + l16) * 32;
#pragma unroll
    for (int nt = 0; nt < 4; ++nt) boff[nt] = quad * 8192 + (wc * 64 + nt * 16 + l16) * 32;

#define RD_A(dst, mt, buf)                                                     \
    do {                                                                       \
        i32x4 lo = *(const i32x4*)(ldsA[buf] + aoff[mt] + sw * 16);            \
        i32x4 hi = *(const i32x4*)(ldsA[buf] + aoff[mt] + (sw ^ 1) * 16);      \
        dst = __builtin_shufflevector(lo, hi, 0, 1, 2, 3, 4, 5, 6, 7);         \
    } while (0)
#define RD_B(dst, nt, buf)                                                     \
    do {                                                                       \
        i32x4 lo = *(const i32x4*)(ldsB[buf] + boff[nt] + sw * 16);            \
        i32x4 hi = *(const i32x4*)(ldsB[buf] + boff[nt] + (sw ^ 1) * 16);      \
        dst = __builtin_shufflevector(lo, hi, 0, 1, 2, 3, 4, 5, 6, 7);         \
    } while (0)
#define MFMA8(a0, a1, m0, m1)                                                  \
    do {                                                                       \
        acc[m0][0] = __builtin_amdgcn_mfma_scale_f32_16x16x128_f8f6f4(a0, bf0, acc[m0][0], 0, 0, 0, 127, 0, 127); \
        acc[m0][1] = __builtin_amdgcn_mfma_scale_f32_16x16x128_f8f6f4(a0, bf1, acc[m0][1], 0, 0, 0, 127, 0, 127); \
        acc[m0][2] = __builtin_amdgcn_mfma_scale_f32_16x16x128_f8f6f4(a0, bf2, acc[m0][2], 0, 0, 0, 127, 0, 127); \
        acc[m0][3] = __builtin_amdgcn_mfma_scale_f32_16x16x128_f8f6f4(a0, bf3, acc[m0][3], 0, 0, 0, 127, 0, 127); \
        acc[m1][0] = __builtin_amdgcn_mfma_scale_f32_16x16x128_f8f6f4(a1, bf0, acc[m1][0], 0, 0, 0, 127, 0, 127); \
        acc[m1][1] = __builtin_amdgcn_mfma_scale_f32_16x16x128_f8f6f4(a1, bf1, acc[m1][1], 0, 0, 0, 127, 0, 127); \
        acc[m1][2] = __builtin_amdgcn_mfma_scale_f32_16x16x128_f8f6f4(a1, bf2, acc[m1][2], 0, 0, 0, 127, 0, 127); \
        acc[m1][3] = __builtin_amdgcn_mfma_scale_f32_16x16x128_f8f6f4(a1, bf3, acc[m1][3], 0, 0, 0, 127, 0, 127); \
    } while (0)
#define SBAR()  __builtin_amdgcn_sched_barrier(0)

    f32x4 acc[8][4];
#pragma unroll
    for (int mt = 0; mt < 8; ++mt)
#pragma unroll
        for (int nt = 0; nt < 4; ++nt)
            acc[mt][nt] = (f32x4){0.f, 0.f, 0.f, 0.f};

    // Prologue: stage tile 0 fully (8 loads) + tile 1 quarter 0 (2 loads);
    // wait vmcnt(2): tile 0 landed, t1.Q0 in flight.
    STAGE(0, 0, 0); STAGE(0, 0, 1); STAGE(0, 0, 2); STAGE(0, 0, 3);
    SBAR();
    STAGE(1, 1, 0);
    SBAR();
    asm volatile("s_waitcnt vmcnt(2)" ::: "memory");
    SBAR();
    __builtin_amdgcn_s_barrier();

#pragma unroll
    for (int t = 0; t < 6; ++t) {
        const int cur = t & 1;
        i32x8 bf0, bf1, bf2, bf3, aE0, aE1, aO0, aO1;

        // Pre-phase reads: all B (8 b128) + A pair0 (4 b128).
        RD_B(bf0, 0, cur); RD_B(bf1, 1, cur); RD_B(bf2, 2, cur); RD_B(bf3, 3, cur);
        RD_A(aE0, 0, cur); RD_A(aE1, 1, cur);

        // ph0: prefetch A pair1; stage Q1(t+1); wait(4); MFMA pair0.
        RD_A(aO0, 2, cur); RD_A(aO1, 3, cur);
        if (t < 5) STAGE(cur ^ 1, t + 1, 1);
        asm volatile("s_waitcnt lgkmcnt(4)" ::: "memory");
        SBAR();
        __builtin_amdgcn_s_setprio(1);
        MFMA8(aE0, aE1, 0, 1);
        __builtin_amdgcn_s_setprio(0);

        // ph1: prefetch A pair2; stage Q2(t+1); wait(4); MFMA pair1.
        RD_A(aE0, 4, cur); RD_A(aE1, 5, cur);
        if (t < 5) STAGE(cur ^ 1, t + 1, 2);
        asm volatile("s_waitcnt lgkmcnt(4)" ::: "memory");
        SBAR();
        __builtin_amdgcn_s_setprio(1);
        MFMA8(aO0, aO1, 2, 3);
        __builtin_amdgcn_s_setprio(0);

        // ph2: prefetch A pair3; stage Q3(t+1); wait(4); MFMA pair2.
        RD_A(aO0, 6, cur); RD_A(aO1, 7, cur);
        if (t < 5) STAGE(cur ^ 1, t + 1, 3);
        asm volatile("s_waitcnt lgkmcnt(4)" ::: "memory");
        SBAR();
        __builtin_amdgcn_s_setprio(1);
        MFMA8(aE0, aE1, 4, 5);
        __builtin_amdgcn_s_setprio(0);

        // ph3: wait(0); MFMA pair3.
        asm volatile("s_waitcnt lgkmcnt(0)" ::: "memory");
        SBAR();
        __builtin_amdgcn_s_setprio(1);
        MFMA8(aO0, aO1, 6, 7);
        __builtin_amdgcn_s_setprio(0);

        // Boundary: mid-barrier (reads of buf[cur] done block-wide) ->
        // issue t+2.Q0 into buf[cur]; counted vmcnt; barrier.
        if (t < 5) {
            __builtin_amdgcn_s_barrier();
            SBAR();
            if (t < 4) {
                STAGE(cur, t + 2, 0);
                SBAR();
                asm volatile("s_waitcnt vmcnt(2)" ::: "memory");
            } else {
                asm volatile("s_waitcnt vmcnt(0)" ::: "memory");
            }
            SBAR();
            __builtin_amdgcn_s_barrier();
        }
    }

    // Epilogue. D layout: col = l16 (ctr idx), row = quad*4 + reg (text idx).
    float rp[8][4];   // [mt][reg] partials over this wave's 64 cols
    float cp[4];      // [nt] partials over this wave's 128 rows
#pragma unroll
    for (int mt = 0; mt < 8; ++mt)
#pragma unroll
        for (int r = 0; r < 4; ++r) rp[mt][r] = 0.f;
#pragma unroll
    for (int nt = 0; nt < 4; ++nt) cp[nt] = 0.f;

#pragma unroll
    for (int mt = 0; mt < 8; ++mt)
#pragma unroll
        for (int nt = 0; nt < 4; ++nt)
#pragma unroll
            for (int r = 0; r < 4; ++r) {
                const float e = __expf(acc[mt][nt][r]);   // S in [-1,1]: no max needed
                rp[mt][r] += e;
                cp[nt]    += e;
            }

#pragma unroll
    for (int mt = 0; mt < 8; ++mt)
#pragma unroll
        for (int r = 0; r < 4; ++r) {
            float v = rp[mt][r];
            v += __shfl_xor(v, 1);
            v += __shfl_xor(v, 2);
            v += __shfl_xor(v, 4);
            v += __shfl_xor(v, 8);
            rp[mt][r] = v;
        }
    if (l16 == 0) {
#pragma unroll
        for (int mt = 0; mt < 8; ++mt)
#pragma unroll
            for (int r = 0; r < 4; ++r)
                atomicAdd(&rowsum[rowBase + wr * 128 + mt * 16 + quad * 4 + r], rp[mt][r]);
    }
#pragma unroll
    for (int nt = 0; nt < 4; ++nt) {
        float v = cp[nt];
        v += __shfl_xor(v, 16);
        v += __shfl_xor(v, 32);
        if (quad == 0)
            atomicAdd(&colsum[colBase + wc * 64 + nt * 16 + l16], v);
    }
}

__global__ __launch_bounds__(1024) void finalize_kernel(
    const float* __restrict__ rowsum, const float* __restrict__ colsum,
    const float* __restrict__ sim, float* __restrict__ out) {
    const int tid = threadIdx.x;
    float acc = 0.f;
#pragma unroll
    for (int i = 0; i < 2; ++i) {
        const int j = (tid + i * 1024) * 4;
        float4 rs = *(const float4*)&rowsum[j];
        float4 cs = *(const float4*)&colsum[j];
        float4 sm = *(const float4*)&sim[j];
        acc += __logf(rs.x) + __logf(rs.y) + __logf(rs.z) + __logf(rs.w);
        acc += __logf(cs.x) + __logf(cs.y) + __logf(cs.z) + __logf(cs.w);
        acc -= 2.f * (sm.x + sm.y + sm.z + sm.w);
    }
#pragma unroll
    for (int off = 1; off < 64; off <<= 1) acc += __shfl_xor(acc, off);
    __shared__ float red[16];
    const int wave = tid >> 6, lane = tid & 63;
    if (lane == 0) red[wave] = acc;
    __syncthreads();
    if (tid == 0) {
        float s = 0.f;
#pragma unroll
        for (int w = 0; w < 16; ++w) s += red[w];
        out[0] = s / (float)BS;
    }
}

extern "C" void kernel_launch(void* const* d_in, const int* in_sizes, int n_in,
                              void* d_out, int out_size, void* d_ws, size_t ws_size,
                              hipStream_t stream) {
    const float* text = (const float*)d_in[0];
    const float* ctr  = (const float*)d_in[1];

    char* ws = (char*)d_ws;
    const size_t embBytes = (size_t)BS * DIM;   // fp8: 6,291,456 bytes each
    unsigned char* tq = (unsigned char*)ws;
    unsigned char* cq = (unsigned char*)(ws + embBytes);
    float* sim    = (float*)(ws + 2 * embBytes);
    float* rowsum = (float*)(ws + 2 * embBytes + BS * sizeof(float));
    float* colsum = (float*)(ws + 2 * embBytes + 2 * BS * sizeof(float));

    normalize_kernel<<<BS / 4, 256, 0, stream>>>(text, ctr, tq, cq, sim, rowsum, colsum);

    gemm_lse_kernel<<<(BS / BM) * (BS / BM), 512, 0, stream>>>(tq, cq, rowsum, colsum);

    finalize_kernel<<<1, 1024, 0, stream>>>(rowsum, colsum, sim, (float*)d_out);
}